// Round 1
// baseline (326.739 us; speedup 1.0000x reference)
//
#include <hip/hip_runtime.h>
#include <math.h>

namespace {

constexpr int B_DIM = 2;
constexpr int C_DIM = 4;
constexpr int D_DIM = 64;
constexpr int H_DIM = 160;
constexpr int W_DIM = 160;

constexpr int TH = 16;
constexpr int TW = 16;
constexpr int HALO = 5;
constexpr int EH = TH + 2 * HALO;  // 26
constexpr int EW = TW + 2 * HALO;  // 26

constexpr int TILES_H = H_DIM / TH;  // 10
constexpr int TILES_W = W_DIM / TW;  // 10
constexpr int NBLOCKS = B_DIM * C_DIM * TILES_H * TILES_W;  // 800

constexpr float C1f = 0.01f * 0.01f;   // 1e-4
constexpr float C2f = 0.03f * 0.03f;   // 9e-4

// per-channel element count: B * D * H * W
constexpr float INV_N = 1.0f / (2.0f * 64.0f * 160.0f * 160.0f);

struct F5 { float v0, v1, v2, v3, v4; };

}  // namespace

__global__ void zero_acc_kernel(float* acc) {
    if (threadIdx.x < C_DIM) acc[threadIdx.x] = 0.0f;
}

__global__ void finalize_kernel(const float* __restrict__ acc, float* __restrict__ out) {
    if (threadIdx.x < C_DIM) out[threadIdx.x] = 1.0f - acc[threadIdx.x] * INV_N;
}

__global__ __launch_bounds__(256, 3) void ssim3d_kernel(
    const float* __restrict__ img1, const float* __restrict__ img2,
    float* __restrict__ acc) {

    // ---- block decode: (b, c, h-tile, w-tile) ----
    const int bid = blockIdx.x;
    const int twi = bid % TILES_W;
    const int thi = (bid / TILES_W) % TILES_H;
    const int c   = (bid / (TILES_W * TILES_H)) % C_DIM;
    const int b   =  bid / (TILES_W * TILES_H * C_DIM);

    const int h0 = thi * TH;
    const int w0 = twi * TW;

    const size_t planeHW = (size_t)H_DIM * W_DIM;
    const size_t volbase = ((size_t)(b * C_DIM + c)) * D_DIM * planeHW;
    const float* __restrict__ p1 = img1 + volbase;
    const float* __restrict__ p2 = img2 + volbase;

    // ---- Gaussian weights (fp64, matches numpy float64 -> float32 path) ----
    float g[11];
    {
        double gd[11];
        double ssum = 0.0;
#pragma unroll
        for (int i = 0; i < 11; ++i) {
            double t = (double)(i - 5);
            gd[i] = exp(-(t * t) / 4.5);  // 2*sigma^2 = 2*1.5^2 = 4.5
            ssum += gd[i];
        }
#pragma unroll
        for (int i = 0; i < 11; ++i) g[i] = (float)(gd[i] / ssum);
    }

    // ---- LDS ----
    __shared__ float  xs[EH][EW + 2];   // 26 x 28, pad vs bank conflicts
    __shared__ float  ys[EH][EW + 2];
    __shared__ float4 midA[EH][TW];     // fields 0..3 after W-conv
    __shared__ float  midB[EH][TW];     // field 4
    __shared__ float  rbuf[4];          // cross-wave reduction

    // ---- register sliding window along D: win[i] = 2D-conv slice (d-5+i) ----
    float win[11][5];
#pragma unroll
    for (int i = 0; i < 11; ++i)
#pragma unroll
        for (int f = 0; f < 5; ++f) win[i][f] = 0.0f;

    const int tid = threadIdx.x;
    const int h_out = tid >> 4;   // 0..15
    const int w_out = tid & 15;   // 0..15

    // compute the 2D-convolved slice s for this tile; returns this thread's
    // (h_out, w_out) 5-field result. s is block-uniform.
    auto compute_slice = [&](int s) -> F5 {
        __syncthreads();  // prior readers of midA/midB done before overwrite
        // phase 1: stage x,y halo tile (zero-padded at H/W edges)
        const size_t sbase = (size_t)s * planeHW;
        for (int e = tid; e < EH * EW; e += 256) {
            const int hh = e / EW;
            const int ww = e - hh * EW;
            const int gh = h0 - HALO + hh;
            const int gw = w0 - HALO + ww;
            const bool ok = ((unsigned)gh < (unsigned)H_DIM) &&
                            ((unsigned)gw < (unsigned)W_DIM);
            float xv = 0.0f, yv = 0.0f;
            if (ok) {
                const size_t gi = sbase + (size_t)gh * W_DIM + gw;
                xv = p1[gi];
                yv = p2[gi];
            }
            xs[hh][ww] = xv;
            ys[hh][ww] = yv;
        }
        __syncthreads();
        // phase 2: W-conv of 5 derived fields at (hh 0..25, w 0..15)
        for (int p = tid; p < EH * TW; p += 256) {
            const int hh = p >> 4;
            const int w  = p & 15;
            float sx = 0.f, sy = 0.f, sxx = 0.f, syy = 0.f, sxy = 0.f;
#pragma unroll
            for (int t = 0; t < 11; ++t) {
                const float x  = xs[hh][w + t];
                const float y  = ys[hh][w + t];
                const float gw_ = g[t];
                const float gx = gw_ * x;
                const float gy = gw_ * y;
                sx += gx;
                sy += gy;
                sxx = fmaf(gx, x, sxx);
                syy = fmaf(gy, y, syy);
                sxy = fmaf(gx, y, sxy);
            }
            midA[hh][w] = make_float4(sx, sy, sxx, syy);
            midB[hh][w] = sxy;
        }
        __syncthreads();
        // phase 3: H-conv at (h_out, w_out), result to registers
        float o0 = 0.f, o1 = 0.f, o2 = 0.f, o3 = 0.f, o4 = 0.f;
#pragma unroll
        for (int t = 0; t < 11; ++t) {
            const float4 a  = midA[h_out + t][w_out];
            const float  bm = midB[h_out + t][w_out];
            const float  gw_ = g[t];
            o0 = fmaf(gw_, a.x, o0);
            o1 = fmaf(gw_, a.y, o1);
            o2 = fmaf(gw_, a.z, o2);
            o3 = fmaf(gw_, a.w, o3);
            o4 = fmaf(gw_, bm, o4);
        }
        return F5{o0, o1, o2, o3, o4};
    };

    float accum = 0.0f;

    // warmup: slices 0..4 land in win[6..10]
    for (int s = 0; s < HALO; ++s) {
#pragma unroll
        for (int i = 0; i < 10; ++i)
#pragma unroll
            for (int f = 0; f < 5; ++f) win[i][f] = win[i + 1][f];
        F5 r = compute_slice(s);
        win[10][0] = r.v0; win[10][1] = r.v1; win[10][2] = r.v2;
        win[10][3] = r.v3; win[10][4] = r.v4;
    }

    for (int d = 0; d < D_DIM; ++d) {
        const int s = d + HALO;
        // shift window
#pragma unroll
        for (int i = 0; i < 10; ++i)
#pragma unroll
            for (int f = 0; f < 5; ++f) win[i][f] = win[i + 1][f];
        if (s < D_DIM) {
            F5 r = compute_slice(s);
            win[10][0] = r.v0; win[10][1] = r.v1; win[10][2] = r.v2;
            win[10][3] = r.v3; win[10][4] = r.v4;
        } else {
#pragma unroll
            for (int f = 0; f < 5; ++f) win[10][f] = 0.0f;
        }
        // D-conv (zero-padded at D edges via zero-filled window slots)
        float o[5] = {0.f, 0.f, 0.f, 0.f, 0.f};
#pragma unroll
        for (int i = 0; i < 11; ++i) {
            const float gw_ = g[i];
#pragma unroll
            for (int f = 0; f < 5; ++f) o[f] = fmaf(gw_, win[i][f], o[f]);
        }
        // SSIM map value
        const float mu1 = o[0], mu2 = o[1];
        const float mu1s = mu1 * mu1;
        const float mu2s = mu2 * mu2;
        const float mu12 = mu1 * mu2;
        const float s1  = o[2] - mu1s;
        const float s2  = o[3] - mu2s;
        const float s12 = o[4] - mu12;
        const float num = (2.0f * mu12 + C1f) * (2.0f * s12 + C2f);
        const float den = (mu1s + mu2s + C1f) * (s1 + s2 + C2f);
        accum += num / den;
    }

    // ---- block reduction, one atomic per block ----
#pragma unroll
    for (int off = 32; off > 0; off >>= 1) accum += __shfl_down(accum, off, 64);
    const int wave = tid >> 6;
    const int lane = tid & 63;
    if (lane == 0) rbuf[wave] = accum;
    __syncthreads();
    if (tid == 0) {
        const float sblk = rbuf[0] + rbuf[1] + rbuf[2] + rbuf[3];
        atomicAdd(&acc[c], sblk);
    }
}

extern "C" void kernel_launch(void* const* d_in, const int* in_sizes, int n_in,
                              void* d_out, int out_size, void* d_ws, size_t ws_size,
                              hipStream_t stream) {
    const float* img1 = (const float*)d_in[0];
    const float* img2 = (const float*)d_in[1];
    float* out = (float*)d_out;
    float* acc = (float*)d_ws;  // 4 floats of scratch

    zero_acc_kernel<<<1, 64, 0, stream>>>(acc);
    ssim3d_kernel<<<NBLOCKS, 256, 0, stream>>>(img1, img2, acc);
    finalize_kernel<<<1, 64, 0, stream>>>(acc, out);
}